// Round 9
// baseline (41.160 us; speedup 1.0000x reference)
//
#include <hip/hip_runtime.h>
#include <hip/hip_bf16.h>

// BarlowTwins loss: logits[b,n,m] = sum_s z1[b,s,n]*z2[b,s,m]  (B=8, S=256, N=M=2048)
// loss = mean_{b,m}( LSE_n(logits[b,:,m]) - logits[b,m,m] )
//
// Round-9 = round-8 + (a) __launch_bounds__(512) with NO min-wave arg -> allocator may
// use up to 256 VGPR (2 waves/SIMD), ending the silent accumulator spill (rounds 4-8
// all showed VGPR_Count=128 < ~190 live; round-7's WRITE_SIZE=88MB proved scratch);
// (b) K-split accumulators: 4 independent 8-deep MFMA chains per wave (acc{0,1}{a,b},
// init -48 each; exp2 on pair-sum) -> 8 chains/SIMD hides MFMA dep latency.
//  K1 prepass: f32 [b][s][n] -> bf16 [b][n][s] K-major; z2 x log2e (round-3 verified).
//  K2 gemm: 256 blocks x 512 thr, 1/CU lockstep (validated memory shape);
//     A staged via 32 global_load_lds_dwordx4/tile with rule-21 both-sides XOR swizzle
//     (source off16 = (lane&31)^(row&31), read off16 = (2ks+kg)^(row&31)) - verified r8.
//     B-frags direct dwordx4 from K-major z2t. No max tracking (headroom ~2^33).
//  K3/K4: merge (log2 S - diag, offset cancels) + mean * ln2.

#define NN 2048
#define SK 256
#define LOG2E 1.4426950408889634f
#define LN2   0.6931471805599453f
#define HOFF  48.0f   // per-half accumulator offset; pair-sum carries -96

typedef __attribute__((ext_vector_type(8))) short short8;
typedef __attribute__((ext_vector_type(16))) float f32x16;

__device__ __forceinline__ unsigned short f2bf(float f) {
    __hip_bfloat16 h = __float2bfloat16(f);
    unsigned short u; __builtin_memcpy(&u, &h, 2); return u;
}

__device__ __forceinline__ float exp2g(float x) {
#if __has_builtin(__builtin_amdgcn_exp2f)
    return __builtin_amdgcn_exp2f(x);
#else
    return exp2f(x);
#endif
}

__device__ __forceinline__ float log2g(float x) {
#if __has_builtin(__builtin_amdgcn_logf)
    return __builtin_amdgcn_logf(x);
#else
    return log2f(x);
#endif
}

__device__ __forceinline__ void gload16(const unsigned short* g, unsigned short* l) {
    // async global->LDS, 16B x 64 lanes; LDS dest = wave-uniform base + lane*16
    __builtin_amdgcn_global_load_lds(
        (const __attribute__((address_space(1))) unsigned int*)(g),
        (__attribute__((address_space(3))) unsigned int*)(l),
        16, 0, 0);
}

// ---------------- K1: transpose + cvt prepass (round-3 verified) ----------------
__global__ __launch_bounds__(256) void transpose_kernel(
    const float* __restrict__ z1, const float* __restrict__ z2,
    unsigned short* __restrict__ z1t, unsigned short* __restrict__ z2t)
{
    __shared__ float lds[64][65];

    const int bid  = blockIdx.x;        // 2048 blocks
    const int arr  = bid >> 10;         // 0: z1, 1: z2
    const int rest = bid & 1023;
    const int b    = rest >> 7;
    const int st   = (rest >> 5) & 3;   // s-tile (4 x 64)
    const int nt   = rest & 31;         // n-tile (32 x 64)

    const float* in = (arr ? z2 : z1) + (size_t)b * SK * NN + (size_t)(st * 64) * NN + nt * 64;
    unsigned short* out = (arr ? z2t : z1t) + (size_t)b * NN * SK + (size_t)(nt * 64) * SK + st * 64;
    const float scale = arr ? LOG2E : 1.0f;

    const int tid = threadIdx.x;
    const int n4 = tid & 15, sl = tid >> 4;
    #pragma unroll
    for (int r = 0; r < 4; ++r) {
        const int s = r * 16 + sl;
        float4 v = *(const float4*)(in + (size_t)s * NN + n4 * 4);
        lds[n4 * 4 + 0][s] = v.x * scale;
        lds[n4 * 4 + 1][s] = v.y * scale;
        lds[n4 * 4 + 2][s] = v.z * scale;
        lds[n4 * 4 + 3][s] = v.w * scale;
    }
    __syncthreads();

    const int nr = tid >> 2, q = tid & 3;
    short8 o0, o1;
    #pragma unroll
    for (int i = 0; i < 8; ++i) o0[i] = (short)f2bf(lds[nr][q * 16 + i]);
    #pragma unroll
    for (int i = 0; i < 8; ++i) o1[i] = (short)f2bf(lds[nr][q * 16 + 8 + i]);
    *(short8*)(out + (size_t)nr * SK + q * 16)     = o0;
    *(short8*)(out + (size_t)nr * SK + q * 16 + 8) = o1;
}

// ---------------- K2: fused GEMM + exp2-sum ----------------
__global__ __launch_bounds__(512) void gemm_lse_kernel(
    const unsigned short* __restrict__ z1t, const unsigned short* __restrict__ z2t,
    float* __restrict__ ws_sum, float* __restrict__ ws_diag)
{
    __shared__ unsigned short ldsA[2][64 * SK];   // 2 x 32 KB, linear 512B rows

    const int bid  = blockIdx.x;
    const int b    = bid & 7;          // XCD-aligned batch
    const int tile = bid >> 3;
    const int mb   = tile & 7;         // 8 m-blocks of 256
    const int ns   = tile >> 3;        // 4 n-splits of 512
    const int tid  = threadIdx.x;
    const int lane = tid & 63;
    const int w    = tid >> 6;
    const int wm   = w >> 1;           // 0..3
    const int wn   = w & 1;            // 0..1
    const int col  = lane & 31;
    const int kg   = lane >> 5;

    const int m0      = mb * 256 + wm * 64;   // strip0; strip1 = +32
    const int mcol0   = m0 + col;
    const int mcol1   = m0 + 32 + col;
    const int n_start = ns * 512;

    const unsigned short* z1b = z1t + (size_t)b * NN * SK;
    const unsigned short* z2b = z2t + (size_t)b * NN * SK;

    // ---- async A staging: tile t = 64 rows x 512B; wave w stages rows 8w..8w+7 ----
    auto stage = [&](int t, int bufi) {
        unsigned short* buf = &ldsA[bufi][0];
        const unsigned short* src = z1b + (size_t)(n_start + 64 * t) * SK;
        #pragma unroll
        for (int q = 0; q < 4; ++q) {
            const int r0   = 8 * w + 2 * q;             // wave-uniform row pair
            const int row  = r0 + (lane >> 5);
            const int off16 = (lane & 31) ^ (row & 31); // pre-swizzled source slot
            gload16(src + (size_t)row * SK + off16 * 8, buf + (size_t)r0 * SK);
        }
    };

    stage(0, 0);   // async; drained by first barrier

    // ---- B fragments: 2 strips x K=256, direct dwordx4 from K-major z2t ----
    short8 bf0[16], bf1[16];
    {
        const unsigned short* b0p = z2b + (size_t)mcol0 * SK + kg * 8;
        const unsigned short* b1p = b0p + 32 * SK;
        #pragma unroll
        for (int ks = 0; ks < 16; ++ks) {
            bf0[ks] = *(const short8*)(b0p + ks * 16);
            bf1[ks] = *(const short8*)(b1p + ks * 16);
        }
    }

    float srun0 = 0.0f, srun1 = 0.0f;

    __syncthreads();   // buf0 staged, B-frags landed

    for (int t = 0; t < 8; ++t) {
        if (t < 7) stage(t + 1, (t + 1) & 1);   // async, overlaps compute below

        // this wave's 32-row subtile: rows 32*wn+col of the tile
        const int rowi  = 32 * wn + col;
        const unsigned short* abase = &ldsA[t & 1][0] + (size_t)rowi * SK;
        const int xr = rowi & 31;

        // K-split: 4 independent 8-deep chains (lo: ks 0-7, hi: ks 8-15)
        f32x16 acc0a, acc0b, acc1a, acc1b;
        #pragma unroll
        for (int r = 0; r < 16; ++r) {
            acc0a[r] = -HOFF; acc0b[r] = -HOFF;
            acc1a[r] = -HOFF; acc1b[r] = -HOFF;
        }

        #pragma unroll
        for (int p = 0; p < 8; ++p) {
            // logical 16B slots: lo = 2p+kg, hi = 2(p+8)+kg; swizzle-read with ^xr
            short8 alo = *(const short8*)(abase + ((((p << 1) | kg) ^ xr) << 3));
            short8 ahi = *(const short8*)(abase + (((((p + 8) << 1) | kg) ^ xr) << 3));
            acc0a = __builtin_amdgcn_mfma_f32_32x32x16_bf16(alo, bf0[p],     acc0a, 0, 0, 0);
            acc1a = __builtin_amdgcn_mfma_f32_32x32x16_bf16(alo, bf1[p],     acc1a, 0, 0, 0);
            acc0b = __builtin_amdgcn_mfma_f32_32x32x16_bf16(ahi, bf0[p + 8], acc0b, 0, 0, 0);
            acc1b = __builtin_amdgcn_mfma_f32_32x32x16_bf16(ahi, bf1[p + 8], acc1b, 0, 0, 0);
        }

        // diagonal capture (pair-sum = logit' - 96; offset cancels in merge)
        const int nsub = n_start + 64 * t + 32 * wn;
        if (nsub == m0) {
            #pragma unroll
            for (int r = 0; r < 16; ++r) {
                const int row = (r & 3) + 8 * (r >> 2) + 4 * kg;
                if (row == col) ws_diag[b * NN + mcol0] = acc0a[r] + acc0b[r];
            }
        }
        if (nsub == m0 + 32) {
            #pragma unroll
            for (int r = 0; r < 16; ++r) {
                const int row = (r & 3) + 8 * (r >> 2) + 4 * kg;
                if (row == col) ws_diag[b * NN + mcol1] = acc1a[r] + acc1b[r];
            }
        }

        // exp2-sum on pair-sums, 4 independent chains per strip
        {
            float e0 = 0, e1 = 0, e2 = 0, e3 = 0;
            #pragma unroll
            for (int r = 0; r < 16; r += 4) {
                e0 += exp2g(acc0a[r]     + acc0b[r]);
                e1 += exp2g(acc0a[r + 1] + acc0b[r + 1]);
                e2 += exp2g(acc0a[r + 2] + acc0b[r + 2]);
                e3 += exp2g(acc0a[r + 3] + acc0b[r + 3]);
            }
            srun0 += (e0 + e1) + (e2 + e3);
        }
        {
            float e0 = 0, e1 = 0, e2 = 0, e3 = 0;
            #pragma unroll
            for (int r = 0; r < 16; r += 4) {
                e0 += exp2g(acc1a[r]     + acc1b[r]);
                e1 += exp2g(acc1a[r + 1] + acc1b[r + 1]);
                e2 += exp2g(acc1a[r + 2] + acc1b[r + 2]);
                e3 += exp2g(acc1a[r + 3] + acc1b[r + 3]);
            }
            srun1 += (e0 + e1) + (e2 + e3);
        }

        __syncthreads();   // drains stage(t+1); all waves done reading buf[t&1]
    }

    srun0 += __shfl_xor(srun0, 32);
    srun1 += __shfl_xor(srun1, 32);
    if (kg == 0) {
        const int slot = ns * 2 + wn;   // 8 n-partials per (b,m)
        ws_sum[(b * 8 + slot) * NN + mcol0] = srun0;
        ws_sum[(b * 8 + slot) * NN + mcol1] = srun1;
    }
}

// ---------------- K3/K4: merge + reduce ----------------
__global__ __launch_bounds__(256) void merge_kernel(
    const float* __restrict__ ws_sum, const float* __restrict__ ws_diag,
    float* __restrict__ partial)
{
    const int gid = blockIdx.x * 256 + threadIdx.x;   // 0..16383
    const int b = gid >> 11, m = gid & (NN - 1);

    float S = 0.0f;
    #pragma unroll
    for (int slot = 0; slot < 8; ++slot)
        S += ws_sum[(b * 8 + slot) * NN + m];
    float c = log2g(S) - ws_diag[gid];   // (LSE' - diag') in log2 units

    #pragma unroll
    for (int d = 1; d < 64; d <<= 1) c += __shfl_xor(c, d);
    __shared__ float red[4];
    if ((threadIdx.x & 63) == 0) red[threadIdx.x >> 6] = c;
    __syncthreads();
    if (threadIdx.x == 0)
        partial[blockIdx.x] = red[0] + red[1] + red[2] + red[3];
}

__global__ void final_kernel(const float* __restrict__ partial, float* __restrict__ out)
{
    float v = partial[threadIdx.x];   // 64 threads
    #pragma unroll
    for (int d = 1; d < 64; d <<= 1) v += __shfl_xor(v, d);
    if (threadIdx.x == 0) out[0] = v * (LN2 / 16384.0f);
}

extern "C" void kernel_launch(void* const* d_in, const int* in_sizes, int n_in,
                              void* d_out, int out_size, void* d_ws, size_t ws_size,
                              hipStream_t stream)
{
    const float* z1 = (const float*)d_in[0];
    const float* z2 = (const float*)d_in[1];
    float* out = (float*)d_out;

    // ws: z1t bf16 [8][2048][256] (8MB) | z2t (8MB) | sum f32 [8][8][2048] | diag [8][2048] | partial[64]
    char* wsb = (char*)d_ws;
    unsigned short* z1t = (unsigned short*)wsb;
    unsigned short* z2t = (unsigned short*)(wsb + (8u << 20));
    float* ws_sum  = (float*)(wsb + (16u << 20));
    float* ws_diag = ws_sum + 8 * 8 * NN;
    float* ws_part = ws_diag + 8 * NN;

    transpose_kernel<<<dim3(2048), dim3(256), 0, stream>>>(z1, z2, z1t, z2t);
    gemm_lse_kernel<<<dim3(256), dim3(512), 0, stream>>>(z1t, z2t, ws_sum, ws_diag);
    merge_kernel<<<dim3(64), dim3(256), 0, stream>>>(ws_sum, ws_diag, ws_part);
    final_kernel<<<dim3(1), dim3(64), 0, stream>>>(ws_part, out);
}

// Round 10
// 38.989 us; speedup vs baseline: 1.0557x; 1.0557x over previous
//
#include <hip/hip_runtime.h>
#include <hip/hip_bf16.h>

// BarlowTwins loss: logits[b,n,m] = sum_s z1[b,s,n]*z2[b,s,m]  (B=8, S=256, N=M=2048)
// loss = mean_{b,m}( LSE_n(logits[b,:,m]) - logits[b,m,m] )
//
// Round-10: counted-vmcnt pipeline (T3/T4-lite) on the verified R8 skeleton.
//  K1: transpose z1 ONLY -> bf16 K-major z1t (1024 blocks; z2 no longer transposed).
//  K2: 256 blocks x 512 thr (1/CU, validated memory shape).
//      - B-frags: coalesced f32 scalar loads from ORIGINAL z2 (x log2e at cvt) -- R4 code.
//      - A: 3 LDS buffers, global_load_lds staging with rule-21 XOR swizzle (R8-verified).
//        Tile t: issue stage(t+2); compute buf[t%3]; s_waitcnt vmcnt(4) + s_barrier.
//        vmcnt NEVER drains to 0 in the loop (m218: counted vs drain0 = +38-73%).
//      - setprio(1) around MFMA cluster (T5).
//      - acc init -96, exp2-sum, no max tracking (headroom ~2^33, verified R2+).
//  K3/K4: merge (log2 S - diag; offset cancels) + mean * ln2.

#define NN 2048
#define SK 256
#define LOG2E 1.4426950408889634f
#define LN2   0.6931471805599453f
#define COFF  96.0f
#define TILE_ELEMS (64 * SK)

typedef __attribute__((ext_vector_type(8))) short short8;
typedef __attribute__((ext_vector_type(16))) float f32x16;

__device__ __forceinline__ unsigned short f2bf(float f) {
    __hip_bfloat16 h = __float2bfloat16(f);
    unsigned short u; __builtin_memcpy(&u, &h, 2); return u;
}

__device__ __forceinline__ float exp2g(float x) {
#if __has_builtin(__builtin_amdgcn_exp2f)
    return __builtin_amdgcn_exp2f(x);
#else
    return exp2f(x);
#endif
}

__device__ __forceinline__ float log2g(float x) {
#if __has_builtin(__builtin_amdgcn_logf)
    return __builtin_amdgcn_logf(x);
#else
    return log2f(x);
#endif
}

__device__ __forceinline__ void gload16(const unsigned short* g, unsigned short* l) {
    // async global->LDS, 16B x 64 lanes; LDS dest = wave-uniform base + lane*16
    __builtin_amdgcn_global_load_lds(
        (const __attribute__((address_space(1))) unsigned int*)(g),
        (__attribute__((address_space(3))) unsigned int*)(l),
        16, 0, 0);
}

// ---------------- K1: transpose + cvt prepass, z1 only ----------------
__global__ __launch_bounds__(256) void transpose_kernel(
    const float* __restrict__ z1, unsigned short* __restrict__ z1t)
{
    __shared__ float lds[64][65];

    const int bid = blockIdx.x;         // 1024 blocks
    const int b   = bid >> 7;
    const int st  = (bid >> 5) & 3;     // s-tile (4 x 64)
    const int nt  = bid & 31;           // n-tile (32 x 64)

    const float* in = z1 + (size_t)b * SK * NN + (size_t)(st * 64) * NN + nt * 64;
    unsigned short* out = z1t + (size_t)b * NN * SK + (size_t)(nt * 64) * SK + st * 64;

    const int tid = threadIdx.x;
    const int n4 = tid & 15, sl = tid >> 4;
    #pragma unroll
    for (int r = 0; r < 4; ++r) {
        const int s = r * 16 + sl;
        float4 v = *(const float4*)(in + (size_t)s * NN + n4 * 4);
        lds[n4 * 4 + 0][s] = v.x;
        lds[n4 * 4 + 1][s] = v.y;
        lds[n4 * 4 + 2][s] = v.z;
        lds[n4 * 4 + 3][s] = v.w;
    }
    __syncthreads();

    const int nr = tid >> 2, q = tid & 3;
    short8 o0, o1;
    #pragma unroll
    for (int i = 0; i < 8; ++i) o0[i] = (short)f2bf(lds[nr][q * 16 + i]);
    #pragma unroll
    for (int i = 0; i < 8; ++i) o1[i] = (short)f2bf(lds[nr][q * 16 + 8 + i]);
    *(short8*)(out + (size_t)nr * SK + q * 16)     = o0;
    *(short8*)(out + (size_t)nr * SK + q * 16 + 8) = o1;
}

// ---------------- K2: fused GEMM + exp2-sum, counted-vmcnt pipeline ----------------
__global__ __launch_bounds__(512) void gemm_lse_kernel(
    const unsigned short* __restrict__ z1t, const float* __restrict__ z2,
    float* __restrict__ ws_sum, float* __restrict__ ws_diag)
{
    __shared__ unsigned short ldsA[3 * TILE_ELEMS];   // 3 x 32 KB

    const int bid  = blockIdx.x;
    const int b    = bid & 7;          // XCD-aligned batch
    const int tile = bid >> 3;
    const int mb   = tile & 7;         // 8 m-blocks of 256
    const int ns   = tile >> 3;        // 4 n-splits of 512
    const int tid  = threadIdx.x;
    const int lane = tid & 63;
    const int w    = tid >> 6;
    const int wm   = w >> 1;           // 0..3
    const int wn   = w & 1;            // 0..1
    const int col  = lane & 31;
    const int kg   = lane >> 5;

    const int m0      = mb * 256 + wm * 64;   // strip0; strip1 = +32
    const int mcol0   = m0 + col;
    const int mcol1   = m0 + 32 + col;
    const int n_start = ns * 512;

    const unsigned short* z1b = z1t + (size_t)b * NN * SK;
    const float*          z2b = z2  + (size_t)b * SK * NN;

    // ---- async A staging: tile t = 64 rows x 512B; wave w stages rows 8w..8w+7 ----
    auto stage = [&](int t, int bufi) {
        unsigned short* buf = &ldsA[bufi * TILE_ELEMS];
        const unsigned short* src = z1b + (size_t)(n_start + 64 * t) * SK;
        #pragma unroll
        for (int q = 0; q < 4; ++q) {
            const int r0    = 8 * w + 2 * q;            // wave-uniform row pair
            const int row   = r0 + (lane >> 5);
            const int off16 = (lane & 31) ^ (row & 31); // pre-swizzled source slot
            gload16(src + (size_t)row * SK + off16 * 8, buf + (size_t)r0 * SK);
        }
    };

    // ---- B fragments: coalesced f32 column loads from original z2, x log2e ----
    short8 bf0[16], bf1[16];
    #pragma unroll
    for (int ks = 0; ks < 16; ++ks) {
        short8 p0, p1;
        #pragma unroll
        for (int j = 0; j < 8; ++j) {
            const int s = ks * 16 + kg * 8 + j;
            p0[j] = (short)f2bf(z2b[(size_t)s * NN + mcol0] * LOG2E);
            p1[j] = (short)f2bf(z2b[(size_t)s * NN + mcol1] * LOG2E);
        }
        bf0[ks] = p0; bf1[ks] = p1;
    }

    // all B loads consumed above; keep stage-loads AFTER them in the VMEM FIFO
    __builtin_amdgcn_sched_barrier(0);
    stage(0, 0);
    stage(1, 1);
    asm volatile("s_waitcnt vmcnt(4)" ::: "memory");   // buf0 landed; buf1 in flight
    __builtin_amdgcn_s_barrier();
    __builtin_amdgcn_sched_barrier(0);

    float srun0 = 0.0f, srun1 = 0.0f;

    for (int t = 0; t < 8; ++t) {
        if (t < 6) stage(t + 2, (t + 2) % 3);   // writes buf last read at tile t-1: safe

        const int rowi = 32 * wn + col;
        const unsigned short* abase = &ldsA[(t % 3) * TILE_ELEMS] + (size_t)rowi * SK;
        const int xr = rowi & 31;

        f32x16 acc0, acc1;
        #pragma unroll
        for (int r = 0; r < 16; ++r) { acc0[r] = -COFF; acc1[r] = -COFF; }

        __builtin_amdgcn_s_setprio(1);
        #pragma unroll
        for (int ks = 0; ks < 16; ++ks) {
            short8 af = *(const short8*)(abase + ((((ks << 1) | kg) ^ xr) << 3));
            acc0 = __builtin_amdgcn_mfma_f32_32x32x16_bf16(af, bf0[ks], acc0, 0, 0, 0);
            acc1 = __builtin_amdgcn_mfma_f32_32x32x16_bf16(af, bf1[ks], acc1, 0, 0, 0);
        }
        __builtin_amdgcn_s_setprio(0);

        // diagonal capture (acc = logit' - 96; offset cancels in merge)
        const int nsub = n_start + 64 * t + 32 * wn;
        if (nsub == m0) {
            #pragma unroll
            for (int r = 0; r < 16; ++r) {
                const int row = (r & 3) + 8 * (r >> 2) + 4 * kg;
                if (row == col) ws_diag[b * NN + mcol0] = acc0[r];
            }
        }
        if (nsub == m0 + 32) {
            #pragma unroll
            for (int r = 0; r < 16; ++r) {
                const int row = (r & 3) + 8 * (r >> 2) + 4 * kg;
                if (row == col) ws_diag[b * NN + mcol1] = acc1[r];
            }
        }

        // exp2-sum, 4 independent chains per strip
        {
            float e0 = 0, e1 = 0, e2 = 0, e3 = 0;
            #pragma unroll
            for (int r = 0; r < 16; r += 4) {
                e0 += exp2g(acc0[r]);     e1 += exp2g(acc0[r + 1]);
                e2 += exp2g(acc0[r + 2]); e3 += exp2g(acc0[r + 3]);
            }
            srun0 += (e0 + e1) + (e2 + e3);
        }
        {
            float e0 = 0, e1 = 0, e2 = 0, e3 = 0;
            #pragma unroll
            for (int r = 0; r < 16; r += 4) {
                e0 += exp2g(acc1[r]);     e1 += exp2g(acc1[r + 1]);
                e2 += exp2g(acc1[r + 2]); e3 += exp2g(acc1[r + 3]);
            }
            srun1 += (e0 + e1) + (e2 + e3);
        }

        // counted end-of-tile wait: next tile's 4 loads landed, tile-after stays in flight
        if (t < 6) {
            asm volatile("s_waitcnt vmcnt(4)" ::: "memory");
            __builtin_amdgcn_s_barrier();
            __builtin_amdgcn_sched_barrier(0);
        } else if (t == 6) {
            asm volatile("s_waitcnt vmcnt(0)" ::: "memory");
            __builtin_amdgcn_s_barrier();
            __builtin_amdgcn_sched_barrier(0);
        }
    }

    srun0 += __shfl_xor(srun0, 32);
    srun1 += __shfl_xor(srun1, 32);
    if (kg == 0) {
        const int slot = ns * 2 + wn;   // 8 n-partials per (b,m)
        ws_sum[(b * 8 + slot) * NN + mcol0] = srun0;
        ws_sum[(b * 8 + slot) * NN + mcol1] = srun1;
    }
}

// ---------------- K3/K4: merge + reduce ----------------
__global__ __launch_bounds__(256) void merge_kernel(
    const float* __restrict__ ws_sum, const float* __restrict__ ws_diag,
    float* __restrict__ partial)
{
    const int gid = blockIdx.x * 256 + threadIdx.x;   // 0..16383
    const int b = gid >> 11, m = gid & (NN - 1);

    float S = 0.0f;
    #pragma unroll
    for (int slot = 0; slot < 8; ++slot)
        S += ws_sum[(b * 8 + slot) * NN + m];
    float c = log2g(S) - ws_diag[gid];   // (LSE' - diag') in log2 units

    #pragma unroll
    for (int d = 1; d < 64; d <<= 1) c += __shfl_xor(c, d);
    __shared__ float red[4];
    if ((threadIdx.x & 63) == 0) red[threadIdx.x >> 6] = c;
    __syncthreads();
    if (threadIdx.x == 0)
        partial[blockIdx.x] = red[0] + red[1] + red[2] + red[3];
}

__global__ void final_kernel(const float* __restrict__ partial, float* __restrict__ out)
{
    float v = partial[threadIdx.x];   // 64 threads
    #pragma unroll
    for (int d = 1; d < 64; d <<= 1) v += __shfl_xor(v, d);
    if (threadIdx.x == 0) out[0] = v * (LN2 / 16384.0f);
}

extern "C" void kernel_launch(void* const* d_in, const int* in_sizes, int n_in,
                              void* d_out, int out_size, void* d_ws, size_t ws_size,
                              hipStream_t stream)
{
    const float* z1 = (const float*)d_in[0];
    const float* z2 = (const float*)d_in[1];
    float* out = (float*)d_out;

    // ws: z1t bf16 [8][2048][256] (8MB) | sum f32 [8][8][2048] | diag [8][2048] | partial[64]
    char* wsb = (char*)d_ws;
    unsigned short* z1t = (unsigned short*)wsb;
    float* ws_sum  = (float*)(wsb + (8u << 20));
    float* ws_diag = ws_sum + 8 * 8 * NN;
    float* ws_part = ws_diag + 8 * NN;

    transpose_kernel<<<dim3(1024), dim3(256), 0, stream>>>(z1, z1t);
    gemm_lse_kernel<<<dim3(256), dim3(512), 0, stream>>>(z1t, z2, ws_sum, ws_diag);
    merge_kernel<<<dim3(64), dim3(256), 0, stream>>>(ws_sum, ws_diag, ws_part);
    final_kernel<<<dim3(1), dim3(64), 0, stream>>>(ws_part, out);
}

// Round 11
// 30.130 us; speedup vs baseline: 1.3661x; 1.2940x over previous
//
#include <hip/hip_runtime.h>
#include <hip/hip_bf16.h>

// BarlowTwins loss: logits[b,n,m] = sum_s z1[b,s,n]*z2[b,s,m]  (B=8, S=256, N=M=2048)
// loss = mean_{b,m}( LSE_n(logits[b,:,m]) - logits[b,m,m] )
//
// Round-11 = R4 machinery (reg-staged f32->bf16->LDS stride-264, dbuf, 1 barrier/tile,
// 1 block/CU lockstep grid, exp2-sum without max tracking) with a NEW decomposition:
//   block = 512 m x 256 n (grid 8b x 4mb x 8ns = 256). Wave w owns 64 m (2 strips)
//   and the FULL 256 n. Removes the wn-duplication of B (z2 read once per col),
//   halves z1 per block (256KB), halves per-thread staging (16 f32/tile), LDS 33.8KB.
//   A-tile = 32n x 256k; all 8 waves read all frags (LDS-read total unchanged).
// B-prologue split in two K-halves with stage(0)/stage(1) between them (latency overlap).
// Bank math (stride 264 = 33 x 16B): write quad=(row+2kc+h)%32, read quad=(row+2ks+kg)%32,
// row spans 0..31 -> permutation, conflict-free (measured 0 conflicts rounds 2/4/5).

#define NN 2048
#define SK 256
#define LDST 264
#define LOG2E 1.4426950408889634f
#define LN2   0.6931471805599453f
#define COFF  96.0f

typedef __attribute__((ext_vector_type(8))) short short8;
typedef __attribute__((ext_vector_type(16))) float f32x16;

__device__ __forceinline__ unsigned short f2bf(float f) {
    __hip_bfloat16 h = __float2bfloat16(f);
    unsigned short u; __builtin_memcpy(&u, &h, 2); return u;
}

__device__ __forceinline__ float exp2g(float x) {
#if __has_builtin(__builtin_amdgcn_exp2f)
    return __builtin_amdgcn_exp2f(x);
#else
    return exp2f(x);
#endif
}

__device__ __forceinline__ float log2g(float x) {
#if __has_builtin(__builtin_amdgcn_logf)
    return __builtin_amdgcn_logf(x);
#else
    return log2f(x);
#endif
}

__global__ __launch_bounds__(512) void gemm_lse_kernel(
    const float* __restrict__ z1, const float* __restrict__ z2,
    float* __restrict__ ws_sum, float* __restrict__ ws_diag)
{
    __shared__ unsigned short lds[2][32 * LDST];   // 2 x 16.9 KB

    const int bid  = blockIdx.x;
    const int b    = bid & 7;          // XCD-aligned batch
    const int tile = bid >> 3;
    const int mb   = tile & 3;         // 4 m-blocks of 512
    const int ns   = tile >> 2;        // 8 n-splits of 256
    const int tid  = threadIdx.x;
    const int lane = tid & 63;
    const int w    = tid >> 6;         // wave 0..7 owns 64 m
    const int col  = lane & 31;
    const int kg   = lane >> 5;

    const int m0      = mb * 512 + w * 64;   // strip0; strip1 = +32
    const int mcol0   = m0 + col;
    const int mcol1   = m0 + 32 + col;
    const int n_start = ns * 256;

    const float* z1b = z1 + (size_t)b * SK * NN;
    const float* z2b = z2 + (size_t)b * SK * NN;

    // ---- A staging: tile = 32 n-rows x 256 k; thread (kc,row) loads 16 f32 ----
    const int kc  = (w << 1) | kg;     // k-chunk 0..15 (16 s each)
    const int row = col;               // n-row 0..31
    float apf[16];
    auto load_A = [&](int t) {
        const float* p = z1b + (size_t)(kc * 16) * NN + (n_start + 32 * t + row);
        #pragma unroll
        for (int j = 0; j < 16; ++j) apf[j] = p[(size_t)j * NN];
    };
    auto store_A = [&](unsigned short* buf) {
        short8 pk0, pk1;
        #pragma unroll
        for (int j = 0; j < 8; ++j) { pk0[j] = (short)f2bf(apf[j]); pk1[j] = (short)f2bf(apf[j + 8]); }
        *(short8*)(buf + row * LDST + kc * 16)     = pk0;
        *(short8*)(buf + row * LDST + kc * 16 + 8) = pk1;
    };

    // ---- prologue: B K-half 0, stage tiles 0/1, B K-half 1 (latency overlap) ----
    short8 bf0[16], bf1[16];
    auto loadB = [&](int ks) {
        short8 p0, p1;
        #pragma unroll
        for (int j = 0; j < 8; ++j) {
            const int s = ks * 16 + kg * 8 + j;
            p0[j] = (short)f2bf(z2b[(size_t)s * NN + mcol0] * LOG2E);
            p1[j] = (short)f2bf(z2b[(size_t)s * NN + mcol1] * LOG2E);
        }
        bf0[ks] = p0; bf1[ks] = p1;
    };

    #pragma unroll
    for (int ks = 0; ks < 8; ++ks) loadB(ks);
    load_A(0);
    store_A(lds[0]);
    load_A(1);
    #pragma unroll
    for (int ks = 8; ks < 16; ++ks) loadB(ks);

    float srun0 = 0.0f, srun1 = 0.0f;

    __syncthreads();   // buf0 visible

    for (int t = 0; t < 8; ++t) {
        const unsigned short* abase = lds[t & 1] + col * LDST + kg * 8;

        f32x16 acc0, acc1;
        #pragma unroll
        for (int r = 0; r < 16; ++r) { acc0[r] = -COFF; acc1[r] = -COFF; }

        #pragma unroll
        for (int ks = 0; ks < 16; ++ks) {
            short8 af = *(const short8*)(abase + ks * 16);
            acc0 = __builtin_amdgcn_mfma_f32_32x32x16_bf16(af, bf0[ks], acc0, 0, 0, 0);
            acc1 = __builtin_amdgcn_mfma_f32_32x32x16_bf16(af, bf1[ks], acc1, 0, 0, 0);
        }

        if (t < 7) store_A(lds[(t + 1) & 1]);   // apf holds tile t+1
        if (t < 6) load_A(t + 2);               // overlaps exp below

        // diagonal capture (acc = logit' - 96; offset cancels in merge)
        const int nsub = n_start + 32 * t;
        if (nsub == m0) {
            #pragma unroll
            for (int r = 0; r < 16; ++r) {
                const int rw = (r & 3) + 8 * (r >> 2) + 4 * kg;
                if (rw == col) ws_diag[b * NN + mcol0] = acc0[r];
            }
        }
        if (nsub == m0 + 32) {
            #pragma unroll
            for (int r = 0; r < 16; ++r) {
                const int rw = (r & 3) + 8 * (r >> 2) + 4 * kg;
                if (rw == col) ws_diag[b * NN + mcol1] = acc1[r];
            }
        }

        // exp2-sum, 4 independent chains per strip
        {
            float e0 = 0, e1 = 0, e2 = 0, e3 = 0;
            #pragma unroll
            for (int r = 0; r < 16; r += 4) {
                e0 += exp2g(acc0[r]);     e1 += exp2g(acc0[r + 1]);
                e2 += exp2g(acc0[r + 2]); e3 += exp2g(acc0[r + 3]);
            }
            srun0 += (e0 + e1) + (e2 + e3);
        }
        {
            float e0 = 0, e1 = 0, e2 = 0, e3 = 0;
            #pragma unroll
            for (int r = 0; r < 16; r += 4) {
                e0 += exp2g(acc1[r]);     e1 += exp2g(acc1[r + 1]);
                e2 += exp2g(acc1[r + 2]); e3 += exp2g(acc1[r + 3]);
            }
            srun1 += (e0 + e1) + (e2 + e3);
        }

        __syncthreads();   // buf[(t+1)&1] visible; all done with buf[t&1]
    }

    // combine kg halves; one writer per m-col (wave owns its cols exclusively)
    srun0 += __shfl_xor(srun0, 32);
    srun1 += __shfl_xor(srun1, 32);
    if (kg == 0) {
        ws_sum[(b * 8 + ns) * NN + mcol0] = srun0;
        ws_sum[(b * 8 + ns) * NN + mcol1] = srun1;
    }
}

__global__ __launch_bounds__(256) void merge_kernel(
    const float* __restrict__ ws_sum, const float* __restrict__ ws_diag,
    float* __restrict__ partial)
{
    const int gid = blockIdx.x * 256 + threadIdx.x;   // 0..16383
    const int b = gid >> 11, m = gid & (NN - 1);

    float S = 0.0f;
    #pragma unroll
    for (int slot = 0; slot < 8; ++slot)
        S += ws_sum[(b * 8 + slot) * NN + m];
    float c = log2g(S) - ws_diag[gid];   // (LSE' - diag') in log2 units

    #pragma unroll
    for (int d = 1; d < 64; d <<= 1) c += __shfl_xor(c, d);
    __shared__ float red[4];
    if ((threadIdx.x & 63) == 0) red[threadIdx.x >> 6] = c;
    __syncthreads();
    if (threadIdx.x == 0)
        partial[blockIdx.x] = red[0] + red[1] + red[2] + red[3];
}

__global__ void final_kernel(const float* __restrict__ partial, float* __restrict__ out)
{
    float v = partial[threadIdx.x];   // 64 threads
    #pragma unroll
    for (int d = 1; d < 64; d <<= 1) v += __shfl_xor(v, d);
    if (threadIdx.x == 0) out[0] = v * (LN2 / 16384.0f);
}

extern "C" void kernel_launch(void* const* d_in, const int* in_sizes, int n_in,
                              void* d_out, int out_size, void* d_ws, size_t ws_size,
                              hipStream_t stream)
{
    const float* z1 = (const float*)d_in[0];
    const float* z2 = (const float*)d_in[1];
    float* ws  = (float*)d_ws;
    float* out = (float*)d_out;

    // ws layout (floats): sum[8][8][2048] | diag[8][2048] | partial[64]
    float* ws_sum  = ws;
    float* ws_diag = ws + 131072;
    float* ws_part = ws + 147456;

    gemm_lse_kernel<<<dim3(256), dim3(512), 0, stream>>>(z1, z2, ws_sum, ws_diag);
    merge_kernel<<<dim3(64), dim3(256), 0, stream>>>(ws_sum, ws_diag, ws_part);
    final_kernel<<<dim3(1), dim3(64), 0, stream>>>(ws_part, out);
}